// Round 14
// baseline (197.921 us; speedup 1.0000x reference)
//
#include <hip/hip_runtime.h>
#include <math.h>

// Problem constants
#define BATCH 8192
#define NFEAT 256
#define NH1   100     // fc1 width (K of fc2)
#define NH2   50      // fc2 width (N of fc2)
#define KP    128     // K padded: 4 MFMA k-steps of 32
#define FPB   8       // features per block (inner loop)
#define RPB   256     // batch rows per block (64 per wave)

typedef __attribute__((ext_vector_type(8))) _Float16 half8;   // MFMA A/B frag
typedef __attribute__((ext_vector_type(2))) _Float16 h2v;     // packed fp16 pair
typedef __attribute__((ext_vector_type(2))) __fp16   fp16x2;  // cvt_pkrtz result
typedef __attribute__((ext_vector_type(4))) float    float4v; // MFMA acc

__device__ __forceinline__ h2v pkrtz(float a, float b) {
    fp16x2 r = __builtin_amdgcn_cvt_pkrtz(a, b);
    return __builtin_bit_cast(h2v, r);
}

// ---- workspace layout (fp32 units from ws start) ----
// w2h : NFEAT*8192 f16 = 4 MB (fragment-ordered, zero-padded)
// w1h/b1h : NFEAT*KP f16 ; tkt : 32 u32 row-block tickets
#define OFF_W1H  (NFEAT * 8192 / 2)
#define OFF_B1H  (OFF_W1H + NFEAT * KP / 2)
#define OFF_TKT  (OFF_B1H + NFEAT * KP / 2)

// ---- prep: one block per feature. Coalesced weight conversion; zeroes
// this feature's out slice; block 0 zeroes the row-block tickets.
__global__ __launch_bounds__(256) void prep(
    const float* __restrict__ W1, const float* __restrict__ b1,
    const float* __restrict__ W2, float* __restrict__ ws,
    float* __restrict__ out)
{
    const int f = blockIdx.x;
    const int t = threadIdx.x;
    _Float16* w1h = (_Float16*)(ws + OFF_W1H) + f * KP;
    _Float16* b1h = (_Float16*)(ws + OFF_B1H) + f * KP;
    _Float16* w2h = (_Float16*)ws + (size_t)f * 8192;

    if (t < KP) {
        w1h[t] = (_Float16)((t < NH1) ? W1[f * NH1 + t] : 0.f);
        b1h[t] = (_Float16)((t < NH1) ? b1[f * NH1 + t] : 0.f);
    }
    if (t < 32) out[f * 32 + t] = 0.f;
    if (f == 0 && t < 32) ((unsigned*)(ws + OFF_TKT))[t] = 0u;

    // w2h[f][kk][nt][lane][j] = f16(W2[f][o=16*nt+(lane&15)][h=32*kk+8*(lane>>4)+j])
    const float* w2g = W2 + (size_t)f * NH2 * NH1;
#pragma unroll
    for (int i = 0; i < 32; ++i) {
        const int e    = i * 256 + t;        // 0..8191
        const int j    = e & 7;
        const int lane = (e >> 3) & 63;
        const int nt   = (e >> 9) & 3;
        const int kk   = e >> 11;
        const int o    = nt * 16 + (lane & 15);
        const int h    = kk * 32 + (lane >> 4) * 8 + j;
        w2h[e] = (_Float16)((o < NH2 && h < NH1) ? w2g[o * NH1 + h] : 0.f);
    }
}

// async 16KB feature-fragment stage: 4 x (256 lanes x 16B) direct
// global->LDS, ZERO staging VGPRs (R11/R12 showed register prefetch state
// spills). Lane-ordered linear copy == wave-uniform-base + lane*16 pattern.
__device__ __forceinline__ void stage_async(
    const _Float16* __restrict__ src, _Float16* dst, int t)
{
#pragma unroll
    for (int i = 0; i < 4; ++i) {
        const _Float16* g = src + (i * 256 + t) * 8;
        _Float16* l       = dst + (i * 256 + t) * 8;
        __builtin_amdgcn_global_load_lds(
            (const __attribute__((address_space(1))) unsigned*)g,
            (__attribute__((address_space(3))) unsigned*)l, 16, 0, 0);
    }
}

// ---- main: block = 4 waves x 256 rows, one feature at a time over FPB=8.
// Double-buffered LDS staged by global_load_lds (issued for f+1 at loop top,
// drained by the single iteration-end barrier). fi-loop is unroll-1 so no
// register state lives across iterations (R12's spill lesson). rp
// accumulates across features -> 1 atomic per row per block. Finish
// (bias+sigmoid) fused via per-rowblock tickets (32 counters x 32 incs).
__global__ __launch_bounds__(256, 3) void nam_mfma(
    const float* __restrict__ x,
    float* __restrict__ ws,
    const float* __restrict__ b2,
    const float* __restrict__ W3,
    const float* __restrict__ bias,
    float* __restrict__ out)
{
    __shared__ _Float16 lds[2][8192];      // 2 x 16 KB fragment buffers

    const int t   = threadIdx.x;
    const int wv  = t >> 6;
    const int l64 = t & 63;
    const int ln  = t & 15;
    const int qd  = (t >> 4) & 3;
    const int rowbase = blockIdx.x * RPB + wv * 64;
    const int f0      = blockIdx.y * FPB;

    const _Float16* w2h = (const _Float16*)ws;
    const _Float16* w1h = (const _Float16*)(ws + OFF_W1H);
    const _Float16* b1h = (const _Float16*)(ws + OFF_B1H);

    int osrc[4];
#pragma unroll
    for (int nt = 0; nt < 4; ++nt) {
        const int o = nt * 16 + ln;
        osrc[nt] = (o < NH2) ? o : 0;      // clamped; killed by wo=0
    }

    stage_async(w2h + (size_t)f0 * 8192, lds[0], t);
    __syncthreads();

    float rp[4][4] = {{0.f}, {0.f}, {0.f}, {0.f}};   // contrib, summed over f

#pragma unroll 1
    for (int fi = 0; fi < FPB; ++fi) {
        const int f = f0 + fi;
        const _Float16* B = lds[fi & 1];

        // kick off next feature's staging; lands by this iter's end barrier
        if (fi + 1 < FPB)
            stage_async(w2h + (size_t)(f + 1) * 8192, lds[(fi + 1) & 1], t);

        // x for this feature (same 64B line across fi -> L1-hot)
        h2v xh[4];
#pragma unroll
        for (int mt = 0; mt < 4; ++mt) {
            const float xs = x[(size_t)(rowbase + mt * 16 + ln) * NFEAT + f];
            xh[mt] = pkrtz(xs, xs);
        }

        float4v acc[4][4];
#pragma unroll
        for (int mt = 0; mt < 4; ++mt)
#pragma unroll
            for (int nt = 0; nt < 4; ++nt) acc[mt][nt] = (float4v){0.f, 0.f, 0.f, 0.f};

        const h2v* wp = (const h2v*)(w1h + f * KP);
        const h2v* cp = (const h2v*)(b1h + f * KP);
        const h2v z2 = (h2v){(_Float16)0.f, (_Float16)0.f};

#pragma unroll
        for (int kk = 0; kk < 4; ++kk) {
            half8 bf[4];
#pragma unroll
            for (int nt = 0; nt < 4; ++nt)
                bf[nt] = *(const half8*)(B + (kk * 4 + nt) * 512 + l64 * 8);

            const int pb = kk * 16 + qd * 4;       // h2v pair index
            const h2v w0 = wp[pb], w1 = wp[pb + 1], w2 = wp[pb + 2], w3 = wp[pb + 3];
            const h2v c0 = cp[pb], c1 = cp[pb + 1], c2 = cp[pb + 2], c3 = cp[pb + 3];

#pragma unroll
            for (int mt = 0; mt < 4; ++mt) {
                half8 af;
                h2v* ap = (h2v*)&af;
                ap[0] = __builtin_elementwise_max(w0 * xh[mt] + c0, z2);
                ap[1] = __builtin_elementwise_max(w1 * xh[mt] + c1, z2);
                ap[2] = __builtin_elementwise_max(w2 * xh[mt] + c2, z2);
                ap[3] = __builtin_elementwise_max(w3 * xh[mt] + c3, z2);
#pragma unroll
                for (int nt = 0; nt < 4; ++nt)
                    acc[mt][nt] = __builtin_amdgcn_mfma_f32_16x16x32_f16(
                        af, bf[nt], acc[mt][nt], 0, 0, 0);
            }
        }

        // epilogue for this f: h2 = relu(acc + b2); rp += h2 * w3
        const float* __restrict__ b2g = b2 + f * NH2;
        const float* __restrict__ w3g = W3 + f * NH2;
#pragma unroll
        for (int nt = 0; nt < 4; ++nt) {
            const int o = nt * 16 + ln;
            const float bo = b2g[osrc[nt]];
            const float wo = (o < NH2) ? w3g[osrc[nt]] : 0.f;
#pragma unroll
            for (int mt = 0; mt < 4; ++mt)
#pragma unroll
                for (int r = 0; r < 4; ++r)
                    rp[mt][r] = fmaf(fmaxf(acc[mt][nt][r] + bo, 0.f), wo, rp[mt][r]);
        }

        __syncthreads();   // drains staging loads + releases buffer fi&1
    }

    // ---- shuffle-reduce rp over the 16 columns, one atomic per row ----
#pragma unroll
    for (int mt = 0; mt < 4; ++mt)
#pragma unroll
        for (int r = 0; r < 4; ++r) {
            float v = rp[mt][r];
            v += __shfl_xor(v, 1);
            v += __shfl_xor(v, 2);
            v += __shfl_xor(v, 4);
            v += __shfl_xor(v, 8);
            if (ln == 0)
                atomicAdd(out + rowbase + mt * 16 + qd * 4 + r, v);
        }

    // ---- fused finish: per-row-block ticket (32 counters, 32 incs each) ----
    __shared__ unsigned last;
    __threadfence();                 // our atomics visible device-wide
    __syncthreads();                 // all 4 waves' atomics issued+fenced
    if (t == 0) {
        unsigned* tkt = (unsigned*)(ws + OFF_TKT) + blockIdx.x;
        last = atomicAdd(tkt, 1u);
    }
    __syncthreads();
    if (last == (unsigned)(gridDim.y - 1)) {
        const float bb = bias[0];
        const int b = blockIdx.x * RPB + t;              // 256 rows, 256 thr
        const float v = atomicAdd(out + b, 0.0f) + bb;   // coherent read
        out[b] = 1.0f / (1.0f + expf(-v));
    }
}

extern "C" void kernel_launch(void* const* d_in, const int* in_sizes, int n_in,
                              void* d_out, int out_size, void* d_ws, size_t ws_size,
                              hipStream_t stream) {
    const float* x    = (const float*)d_in[0];
    const float* W1   = (const float*)d_in[1];
    const float* b1   = (const float*)d_in[2];
    const float* W2   = (const float*)d_in[3];
    const float* b2   = (const float*)d_in[4];
    const float* W3   = (const float*)d_in[5];
    const float* bias = (const float*)d_in[6];
    float* out = (float*)d_out;
    float* ws  = (float*)d_ws;   // ~4.3 MB used

    prep<<<NFEAT, 256, 0, stream>>>(W1, b1, W2, ws, out);

    nam_mfma<<<dim3(BATCH / RPB, NFEAT / FPB), 256, 0, stream>>>(
        x, ws, b2, W3, bias, out);
}

// Round 15
// 197.354 us; speedup vs baseline: 1.0029x; 1.0029x over previous
//
#include <hip/hip_runtime.h>
#include <math.h>

// Problem constants
#define BATCH 8192
#define NFEAT 256
#define NH1   100     // fc1 width (K of fc2)
#define NH2   50      // fc2 width (N of fc2)
#define KP    128     // K padded: 4 MFMA k-steps of 32
#define FPB   8       // features per block (inner loop)
#define RPB   256     // batch rows per block (64 per wave)

typedef __attribute__((ext_vector_type(8))) _Float16 half8;   // MFMA A/B frag
typedef __attribute__((ext_vector_type(2))) _Float16 h2v;     // packed fp16 pair
typedef __attribute__((ext_vector_type(2))) __fp16   fp16x2;  // cvt_pkrtz result
typedef __attribute__((ext_vector_type(4))) float    float4v; // MFMA acc

__device__ __forceinline__ h2v pkrtz(float a, float b) {
    fp16x2 r = __builtin_amdgcn_cvt_pkrtz(a, b);
    return __builtin_bit_cast(h2v, r);
}

// ---- workspace layout (fp32 units from ws start) ----
// w2h : NFEAT*8192 f16 = 4 MB (fragment-ordered, zero-padded)
// w1h/b1h : NFEAT*KP f16 ; tkt : 32 u32 row-block tickets
#define OFF_W1H  (NFEAT * 8192 / 2)
#define OFF_B1H  (OFF_W1H + NFEAT * KP / 2)
#define OFF_TKT  (OFF_B1H + NFEAT * KP / 2)

// ---- prep: one block per feature. Coalesced weight conversion; zeroes
// this feature's out slice; block 0 zeroes the row-block tickets.
__global__ __launch_bounds__(256) void prep(
    const float* __restrict__ W1, const float* __restrict__ b1,
    const float* __restrict__ W2, float* __restrict__ ws,
    float* __restrict__ out)
{
    const int f = blockIdx.x;
    const int t = threadIdx.x;
    _Float16* w1h = (_Float16*)(ws + OFF_W1H) + f * KP;
    _Float16* b1h = (_Float16*)(ws + OFF_B1H) + f * KP;
    _Float16* w2h = (_Float16*)ws + (size_t)f * 8192;

    if (t < KP) {
        w1h[t] = (_Float16)((t < NH1) ? W1[f * NH1 + t] : 0.f);
        b1h[t] = (_Float16)((t < NH1) ? b1[f * NH1 + t] : 0.f);
    }
    if (t < 32) out[f * 32 + t] = 0.f;
    if (f == 0 && t < 32) ((unsigned*)(ws + OFF_TKT))[t] = 0u;

    // w2h[f][kk][nt][lane][j] = f16(W2[f][o=16*nt+(lane&15)][h=32*kk+8*(lane>>4)+j])
    const float* w2g = W2 + (size_t)f * NH2 * NH1;
#pragma unroll
    for (int i = 0; i < 32; ++i) {
        const int e    = i * 256 + t;        // 0..8191
        const int j    = e & 7;
        const int lane = (e >> 3) & 63;
        const int nt   = (e >> 9) & 3;
        const int kk   = e >> 11;
        const int o    = nt * 16 + (lane & 15);
        const int h    = kk * 32 + (lane >> 4) * 8 + j;
        w2h[e] = (_Float16)((o < NH2 && h < NH1) ? w2g[o * NH1 + h] : 0.f);
    }
}

// ---- main: EXACT R13 body (59 us known-good: single 16KB LDS buffer,
// sync int4 staging between two barriers, zero persistent staging regs,
// unroll-1 fi-loop) + ONLY the ticket-fused finish appended (A/B test:
// isolates the ticket variable from R14's async-staging variable).
__global__ __launch_bounds__(256, 3) void nam_mfma(
    const float* __restrict__ x,
    float* __restrict__ ws,
    const float* __restrict__ b2,
    const float* __restrict__ W3,
    const float* __restrict__ bias,
    float* __restrict__ out)
{
    __shared__ _Float16 Bsh[8192];         // one 16 KB fragment buffer

    const int t   = threadIdx.x;
    const int wv  = t >> 6;
    const int l64 = t & 63;
    const int ln  = t & 15;
    const int qd  = (t >> 4) & 3;
    const int rowbase = blockIdx.x * RPB + wv * 64;
    const int f0      = blockIdx.y * FPB;

    const _Float16* w2h = (const _Float16*)ws;
    const _Float16* w1h = (const _Float16*)(ws + OFF_W1H);
    const _Float16* b1h = (const _Float16*)(ws + OFF_B1H);

    int osrc[4];
#pragma unroll
    for (int nt = 0; nt < 4; ++nt) {
        const int o = nt * 16 + ln;
        osrc[nt] = (o < NH2) ? o : 0;      // clamped; killed by wo=0
    }

    float rp[4][4] = {{0.f}, {0.f}, {0.f}, {0.f}};   // contrib, summed over f

#pragma unroll 1
    for (int fi = 0; fi < FPB; ++fi) {
        const int f = f0 + fi;

        // ---- stage this feature's fragments: 4 x int4 per thread ----
        if (fi > 0) __syncthreads();       // release buffer from previous f
        {
            const int4* src = (const int4*)(w2h + (size_t)f * 8192);
            int4* dst = (int4*)Bsh;
#pragma unroll
            for (int i = 0; i < 4; ++i) dst[i * 256 + t] = src[i * 256 + t];
        }
        __syncthreads();

        // x for this feature (same 64B line across fi -> L1-hot)
        h2v xh[4];
#pragma unroll
        for (int mt = 0; mt < 4; ++mt) {
            const float xs = x[(size_t)(rowbase + mt * 16 + ln) * NFEAT + f];
            xh[mt] = pkrtz(xs, xs);
        }

        float4v acc[4][4];
#pragma unroll
        for (int mt = 0; mt < 4; ++mt)
#pragma unroll
            for (int nt = 0; nt < 4; ++nt) acc[mt][nt] = (float4v){0.f, 0.f, 0.f, 0.f};

        const h2v* wp = (const h2v*)(w1h + f * KP);
        const h2v* cp = (const h2v*)(b1h + f * KP);
        const h2v z2 = (h2v){(_Float16)0.f, (_Float16)0.f};

#pragma unroll
        for (int kk = 0; kk < 4; ++kk) {
            half8 bf[4];
#pragma unroll
            for (int nt = 0; nt < 4; ++nt)
                bf[nt] = *(const half8*)(Bsh + (kk * 4 + nt) * 512 + l64 * 8);

            const int pb = kk * 16 + qd * 4;       // h2v pair index
            const h2v w0 = wp[pb], w1 = wp[pb + 1], w2 = wp[pb + 2], w3 = wp[pb + 3];
            const h2v c0 = cp[pb], c1 = cp[pb + 1], c2 = cp[pb + 2], c3 = cp[pb + 3];

#pragma unroll
            for (int mt = 0; mt < 4; ++mt) {
                half8 af;
                h2v* ap = (h2v*)&af;
                ap[0] = __builtin_elementwise_max(w0 * xh[mt] + c0, z2);
                ap[1] = __builtin_elementwise_max(w1 * xh[mt] + c1, z2);
                ap[2] = __builtin_elementwise_max(w2 * xh[mt] + c2, z2);
                ap[3] = __builtin_elementwise_max(w3 * xh[mt] + c3, z2);
#pragma unroll
                for (int nt = 0; nt < 4; ++nt)
                    acc[mt][nt] = __builtin_amdgcn_mfma_f32_16x16x32_f16(
                        af, bf[nt], acc[mt][nt], 0, 0, 0);
            }
        }

        // epilogue for this f: h2 = relu(acc + b2); rp += h2 * w3
        const float* __restrict__ b2g = b2 + f * NH2;
        const float* __restrict__ w3g = W3 + f * NH2;
#pragma unroll
        for (int nt = 0; nt < 4; ++nt) {
            const int o = nt * 16 + ln;
            const float bo = b2g[osrc[nt]];
            const float wo = (o < NH2) ? w3g[osrc[nt]] : 0.f;
#pragma unroll
            for (int mt = 0; mt < 4; ++mt)
#pragma unroll
                for (int r = 0; r < 4; ++r)
                    rp[mt][r] = fmaf(fmaxf(acc[mt][nt][r] + bo, 0.f), wo, rp[mt][r]);
        }
    }

    // ---- shuffle-reduce rp over the 16 columns, one atomic per row ----
#pragma unroll
    for (int mt = 0; mt < 4; ++mt)
#pragma unroll
        for (int r = 0; r < 4; ++r) {
            float v = rp[mt][r];
            v += __shfl_xor(v, 1);
            v += __shfl_xor(v, 2);
            v += __shfl_xor(v, 4);
            v += __shfl_xor(v, 8);
            if (ln == 0)
                atomicAdd(out + rowbase + mt * 16 + qd * 4 + r, v);
        }

    // ---- fused finish: per-row-block ticket (32 counters, 32 incs each) ----
    __shared__ unsigned last;
    __threadfence();                 // order our out-atomics before ticket
    __syncthreads();                 // all 4 waves' atomics issued+fenced
    if (t == 0) {
        unsigned* tkt = (unsigned*)(ws + OFF_TKT) + blockIdx.x;
        last = atomicAdd(tkt, 1u);
    }
    __syncthreads();
    if (last == (unsigned)(gridDim.y - 1)) {
        const float bb = bias[0];
        const int b = blockIdx.x * RPB + t;              // 256 rows, 256 thr
        const float v = atomicAdd(out + b, 0.0f) + bb;   // coherent read
        out[b] = 1.0f / (1.0f + expf(-v));
    }
}

extern "C" void kernel_launch(void* const* d_in, const int* in_sizes, int n_in,
                              void* d_out, int out_size, void* d_ws, size_t ws_size,
                              hipStream_t stream) {
    const float* x    = (const float*)d_in[0];
    const float* W1   = (const float*)d_in[1];
    const float* b1   = (const float*)d_in[2];
    const float* W2   = (const float*)d_in[3];
    const float* b2   = (const float*)d_in[4];
    const float* W3   = (const float*)d_in[5];
    const float* bias = (const float*)d_in[6];
    float* out = (float*)d_out;
    float* ws  = (float*)d_ws;   // ~4.3 MB used

    prep<<<NFEAT, 256, 0, stream>>>(W1, b1, W2, ws, out);

    nam_mfma<<<dim3(BATCH / RPB, NFEAT / FPB), 256, 0, stream>>>(
        x, ws, b2, W3, bias, out);
}

// Round 16
// 170.863 us; speedup vs baseline: 1.1584x; 1.1550x over previous
//
#include <hip/hip_runtime.h>
#include <math.h>

// Problem constants
#define BATCH 8192
#define NFEAT 256
#define NH1   100     // fc1 width (K of fc2)
#define NH2   50      // fc2 width (N of fc2)
#define KP    128     // K padded: 4 MFMA k-steps of 32
#define FPB   8       // features per block (inner loop)
#define RPB   256     // batch rows per block (64 per wave)

typedef __attribute__((ext_vector_type(8))) _Float16 half8;   // MFMA A/B frag
typedef __attribute__((ext_vector_type(2))) _Float16 h2v;     // packed fp16 pair
typedef __attribute__((ext_vector_type(2))) __fp16   fp16x2;  // cvt_pkrtz result
typedef __attribute__((ext_vector_type(4))) float    float4v; // MFMA acc

__device__ __forceinline__ h2v pkrtz(float a, float b) {
    fp16x2 r = __builtin_amdgcn_cvt_pkrtz(a, b);
    return __builtin_bit_cast(h2v, r);
}

// ---- workspace layout (fp32 units from ws start) ----
// w2h : NFEAT*8192 f16 = 4 MB (fragment-ordered, zero-padded)
// w1h/b1h : NFEAT*KP f16 (zero-padded)
#define OFF_W1H  (NFEAT * 8192 / 2)
#define OFF_B1H  (OFF_W1H + NFEAT * KP / 2)

// ---- prep v2: grid = (4 kk-quarters, NFEAT features). Each block loads its
// 50x32 W2 slice COALESCED (two 128B segments per wave) into LDS (stride 40
// -> max 2-way bank aliasing = free), then emits fragment-ordered fp16 with
// fully-coalesced 2B stores. R13's prep did per-lane scattered 4B reads of
// cold W2 at 1 wave/SIMD -> ~60 us; this is 4x waves + coalesced -> ~5-8 us.
__global__ __launch_bounds__(256) void prep(
    const float* __restrict__ W1, const float* __restrict__ b1,
    const float* __restrict__ W2, float* __restrict__ ws,
    float* __restrict__ out)
{
    __shared__ float l2[NH2 * 40];       // 8 KB, stride 40
    const int q = blockIdx.x;            // kk quarter 0..3
    const int f = blockIdx.y;
    const int t = threadIdx.x;

    if (q == 0) {
        _Float16* w1h = (_Float16*)(ws + OFF_W1H) + f * KP;
        _Float16* b1h = (_Float16*)(ws + OFF_B1H) + f * KP;
        if (t < KP) {
            w1h[t] = (_Float16)((t < NH1) ? W1[f * NH1 + t] : 0.f);
            b1h[t] = (_Float16)((t < NH1) ? b1[f * NH1 + t] : 0.f);
        }
        if (t < 32) out[f * 32 + t] = 0.f;
    }

    // load W2[f][o][q*32+hh] for o<50, hh<32 (masked h<100)
    const float* __restrict__ w2g = W2 + (size_t)f * NH2 * NH1;
#pragma unroll
    for (int i = 0; i < 7; ++i) {
        const int idx = i * 256 + t;
        if (idx < NH2 * 32) {
            const int o = idx >> 5, hh = idx & 31, h = q * 32 + hh;
            l2[o * 40 + hh] = (h < NH1) ? w2g[o * NH1 + h] : 0.f;
        }
    }
    __syncthreads();

    // emit w2h[f][kk=q][nt][lane][j]; consecutive e -> coalesced 2B stores
    _Float16* w2h = (_Float16*)ws + (size_t)f * 8192 + q * 2048;
#pragma unroll
    for (int i = 0; i < 8; ++i) {
        const int el   = i * 256 + t;          // 0..2047
        const int j    = el & 7;
        const int lane = (el >> 3) & 63;
        const int nt   = (el >> 9) & 3;
        const int o    = nt * 16 + (lane & 15);
        const int hl   = (lane >> 4) * 8 + j;
        const float v  = (o < NH2) ? l2[o * 40 + hl] : 0.f;
        w2h[el] = (_Float16)v;
    }
}

// ---- main: EXACT R13 body (59 us known-good). Only change: launch_bounds
// (256,3)->(256,4) to push total regs (80 arch + 64 acc = 144) toward <=128
// for 4 blocks/CU. Spill canary = WRITE_SIZE. No ticket/fence (R15 A/B:
// the device-scope fence epilogue dilates the kernel 2.2x).
__global__ __launch_bounds__(256, 4) void nam_mfma(
    const float* __restrict__ x,
    const float* __restrict__ ws,
    const float* __restrict__ b2,
    const float* __restrict__ W3,
    float* __restrict__ out)
{
    __shared__ _Float16 Bsh[8192];         // one 16 KB fragment buffer

    const int t   = threadIdx.x;
    const int wv  = t >> 6;
    const int l64 = t & 63;
    const int ln  = t & 15;
    const int qd  = (t >> 4) & 3;
    const int rowbase = blockIdx.x * RPB + wv * 64;
    const int f0      = blockIdx.y * FPB;

    const _Float16* w2h = (const _Float16*)ws;
    const _Float16* w1h = (const _Float16*)(ws + OFF_W1H);
    const _Float16* b1h = (const _Float16*)(ws + OFF_B1H);

    int osrc[4];
#pragma unroll
    for (int nt = 0; nt < 4; ++nt) {
        const int o = nt * 16 + ln;
        osrc[nt] = (o < NH2) ? o : 0;      // clamped; killed by wo=0
    }

    float rp[4][4] = {{0.f}, {0.f}, {0.f}, {0.f}};   // contrib, summed over f

#pragma unroll 1
    for (int fi = 0; fi < FPB; ++fi) {
        const int f = f0 + fi;

        // ---- stage this feature's fragments: 4 x int4 per thread ----
        if (fi > 0) __syncthreads();       // release buffer from previous f
        {
            const int4* src = (const int4*)(w2h + (size_t)f * 8192);
            int4* dst = (int4*)Bsh;
#pragma unroll
            for (int i = 0; i < 4; ++i) dst[i * 256 + t] = src[i * 256 + t];
        }
        __syncthreads();

        // x for this feature (same 64B line across fi -> L1-hot)
        h2v xh[4];
#pragma unroll
        for (int mt = 0; mt < 4; ++mt) {
            const float xs = x[(size_t)(rowbase + mt * 16 + ln) * NFEAT + f];
            xh[mt] = pkrtz(xs, xs);
        }

        float4v acc[4][4];
#pragma unroll
        for (int mt = 0; mt < 4; ++mt)
#pragma unroll
            for (int nt = 0; nt < 4; ++nt) acc[mt][nt] = (float4v){0.f, 0.f, 0.f, 0.f};

        const h2v* wp = (const h2v*)(w1h + f * KP);
        const h2v* cp = (const h2v*)(b1h + f * KP);
        const h2v z2 = (h2v){(_Float16)0.f, (_Float16)0.f};

#pragma unroll
        for (int kk = 0; kk < 4; ++kk) {
            half8 bf[4];
#pragma unroll
            for (int nt = 0; nt < 4; ++nt)
                bf[nt] = *(const half8*)(Bsh + (kk * 4 + nt) * 512 + l64 * 8);

            const int pb = kk * 16 + qd * 4;       // h2v pair index
            const h2v w0 = wp[pb], w1 = wp[pb + 1], w2 = wp[pb + 2], w3 = wp[pb + 3];
            const h2v c0 = cp[pb], c1 = cp[pb + 1], c2 = cp[pb + 2], c3 = cp[pb + 3];

#pragma unroll
            for (int mt = 0; mt < 4; ++mt) {
                half8 af;
                h2v* ap = (h2v*)&af;
                ap[0] = __builtin_elementwise_max(w0 * xh[mt] + c0, z2);
                ap[1] = __builtin_elementwise_max(w1 * xh[mt] + c1, z2);
                ap[2] = __builtin_elementwise_max(w2 * xh[mt] + c2, z2);
                ap[3] = __builtin_elementwise_max(w3 * xh[mt] + c3, z2);
#pragma unroll
                for (int nt = 0; nt < 4; ++nt)
                    acc[mt][nt] = __builtin_amdgcn_mfma_f32_16x16x32_f16(
                        af, bf[nt], acc[mt][nt], 0, 0, 0);
            }
        }

        // epilogue for this f: h2 = relu(acc + b2); rp += h2 * w3
        const float* __restrict__ b2g = b2 + f * NH2;
        const float* __restrict__ w3g = W3 + f * NH2;
#pragma unroll
        for (int nt = 0; nt < 4; ++nt) {
            const int o = nt * 16 + ln;
            const float bo = b2g[osrc[nt]];
            const float wo = (o < NH2) ? w3g[osrc[nt]] : 0.f;
#pragma unroll
            for (int mt = 0; mt < 4; ++mt)
#pragma unroll
                for (int r = 0; r < 4; ++r)
                    rp[mt][r] = fmaf(fmaxf(acc[mt][nt][r] + bo, 0.f), wo, rp[mt][r]);
        }
    }

    // ---- shuffle-reduce rp over the 16 columns, one atomic per row ----
#pragma unroll
    for (int mt = 0; mt < 4; ++mt)
#pragma unroll
        for (int r = 0; r < 4; ++r) {
            float v = rp[mt][r];
            v += __shfl_xor(v, 1);
            v += __shfl_xor(v, 2);
            v += __shfl_xor(v, 4);
            v += __shfl_xor(v, 8);
            if (ln == 0)
                atomicAdd(out + rowbase + mt * 16 + qd * 4 + r, v);
        }
}

__global__ __launch_bounds__(256) void nam_finish(
    float* __restrict__ out, const float* __restrict__ bias)
{
    const int b = blockIdx.x * blockDim.x + threadIdx.x;
    out[b] = 1.0f / (1.0f + expf(-(out[b] + bias[0])));
}

extern "C" void kernel_launch(void* const* d_in, const int* in_sizes, int n_in,
                              void* d_out, int out_size, void* d_ws, size_t ws_size,
                              hipStream_t stream) {
    const float* x    = (const float*)d_in[0];
    const float* W1   = (const float*)d_in[1];
    const float* b1   = (const float*)d_in[2];
    const float* W2   = (const float*)d_in[3];
    const float* b2   = (const float*)d_in[4];
    const float* W3   = (const float*)d_in[5];
    const float* bias = (const float*)d_in[6];
    float* out = (float*)d_out;
    float* ws  = (float*)d_ws;   // ~4.3 MB used

    prep<<<dim3(4, NFEAT), 256, 0, stream>>>(W1, b1, W2, ws, out);

    nam_mfma<<<dim3(BATCH / RPB, NFEAT / FPB), 256, 0, stream>>>(
        x, ws, b2, W3, out);

    nam_finish<<<BATCH / 256, 256, 0, stream>>>(out, bias);
}

// Round 17
// 155.051 us; speedup vs baseline: 1.2765x; 1.1020x over previous
//
#include <hip/hip_runtime.h>
#include <math.h>

// Problem constants
#define BATCH 8192
#define NFEAT 256
#define NH1   100     // fc1 width (K of fc2)
#define NH2   50      // fc2 width (N of fc2)
#define FPB   8       // features per block (inner loop)
#define RPB   256     // batch rows per block (64 per wave)

typedef __attribute__((ext_vector_type(8))) _Float16 half8;   // MFMA A/B frag
typedef __attribute__((ext_vector_type(2))) _Float16 h2v;     // packed fp16 pair
typedef __attribute__((ext_vector_type(2))) __fp16   fp16x2;  // cvt_pkrtz result
typedef __attribute__((ext_vector_type(4))) float    float4v; // MFMA acc

__device__ __forceinline__ h2v pkrtz(float a, float b) {
    fp16x2 r = __builtin_amdgcn_cvt_pkrtz(a, b);
    return __builtin_bit_cast(h2v, r);
}

// ---- main: ZERO workspace use (R16 ledger: every ws-using round pays a
// ~70us non-main tax that R1's ws-free graph didn't; prep speed was
// irrelevant). Block = 4 waves x 256 rows, fi-loop over 8 features.
// Per f: stage raw fp32 W2[f] (20KB) into LDS coalesced, build B-frags
// from LDS (stride-100 rows -> 2-way bank aliasing = free) + pkrtz.
// fc1 weights fp32 from global (L1-hot) + pkrtz. kk=3 handled exactly by
// masking the A-fragment to zero for k>=100 (B garbage there multiplies 0).
// unroll-1 fi loop, no persistent staging regs (R12/R16 spill lessons).
__global__ __launch_bounds__(256, 3) void nam_mfma(
    const float* __restrict__ x,
    const float* __restrict__ W1, const float* __restrict__ b1,
    const float* __restrict__ W2, const float* __restrict__ b2,
    const float* __restrict__ W3,
    float* __restrict__ out)
{
    __shared__ float Wsh[5120];            // 20 KB: W2[f] rows, stride 100

    const int t   = threadIdx.x;
    const int wv  = t >> 6;
    const int l64 = t & 63;
    const int ln  = t & 15;
    const int qd  = (t >> 4) & 3;
    const int rowbase = blockIdx.x * RPB + wv * 64;
    const int f0      = blockIdx.y * FPB;

    int osrc[4];
#pragma unroll
    for (int nt = 0; nt < 4; ++nt) {
        const int o = nt * 16 + ln;
        osrc[nt] = (o < NH2) ? o : 0;      // clamped; killed by wo=0
    }

    const h2v z2 = (h2v){(_Float16)0.f, (_Float16)0.f};
    float rp[4][4] = {{0.f}, {0.f}, {0.f}, {0.f}};   // contrib, summed over f

#pragma unroll 1
    for (int fi = 0; fi < FPB; ++fi) {
        const int f = f0 + fi;
        const float* __restrict__ w1g = W1 + f * NH1;
        const float* __restrict__ b1g = b1 + f * NH1;

        // ---- stage W2[f] fp32 into LDS, coalesced (5 x float4/thread) ----
        if (fi > 0) __syncthreads();       // release LDS from previous f
        {
            const float4* src = (const float4*)(W2 + (size_t)f * NH2 * NH1);
            float4* dst = (float4*)Wsh;
            const float4 z4 = make_float4(0.f, 0.f, 0.f, 0.f);
#pragma unroll
            for (int i = 0; i < 5; ++i) {
                const int idx = i * 256 + t;           // 0..1279
                dst[idx] = (idx < 1250) ? src[idx] : z4;
            }
        }
        __syncthreads();

        // x for this feature (same 64B line across fi -> L1-hot)
        h2v xh[4];
#pragma unroll
        for (int mt = 0; mt < 4; ++mt) {
            const float xs = x[(size_t)(rowbase + mt * 16 + ln) * NFEAT + f];
            xh[mt] = pkrtz(xs, xs);
        }

        float4v acc[4][4];
#pragma unroll
        for (int mt = 0; mt < 4; ++mt)
#pragma unroll
            for (int nt = 0; nt < 4; ++nt) acc[mt][nt] = (float4v){0.f, 0.f, 0.f, 0.f};

        // ---- kk = 0..2 : full 32-wide K steps ----
#pragma unroll
        for (int kk = 0; kk < 3; ++kk) {
            const int kb = kk * 32 + qd * 8;          // <= 88, +7 in-bounds

            const float4 wA = *(const float4*)(w1g + kb);
            const float4 wB = *(const float4*)(w1g + kb + 4);
            const float4 cA = *(const float4*)(b1g + kb);
            const float4 cB = *(const float4*)(b1g + kb + 4);
            const h2v wh0 = pkrtz(wA.x, wA.y), wh1 = pkrtz(wA.z, wA.w);
            const h2v wh2 = pkrtz(wB.x, wB.y), wh3 = pkrtz(wB.z, wB.w);
            const h2v ch0 = pkrtz(cA.x, cA.y), ch1 = pkrtz(cA.z, cA.w);
            const h2v ch2 = pkrtz(cB.x, cB.y), ch3 = pkrtz(cB.z, cB.w);

            half8 bf[4];
#pragma unroll
            for (int nt = 0; nt < 4; ++nt) {
                const float* rowp = Wsh + osrc[nt] * NH1 + kb;   // 16B-aligned
                const float4 u0 = *(const float4*)(rowp);
                const float4 u1 = *(const float4*)(rowp + 4);
                h2v* bp = (h2v*)&bf[nt];
                bp[0] = pkrtz(u0.x, u0.y); bp[1] = pkrtz(u0.z, u0.w);
                bp[2] = pkrtz(u1.x, u1.y); bp[3] = pkrtz(u1.z, u1.w);
            }

#pragma unroll
            for (int mt = 0; mt < 4; ++mt) {
                half8 af;
                h2v* ap = (h2v*)&af;
                ap[0] = __builtin_elementwise_max(wh0 * xh[mt] + ch0, z2);
                ap[1] = __builtin_elementwise_max(wh1 * xh[mt] + ch1, z2);
                ap[2] = __builtin_elementwise_max(wh2 * xh[mt] + ch2, z2);
                ap[3] = __builtin_elementwise_max(wh3 * xh[mt] + ch3, z2);
#pragma unroll
                for (int nt = 0; nt < 4; ++nt)
                    acc[mt][nt] = __builtin_amdgcn_mfma_f32_16x16x32_f16(
                        af, bf[nt], acc[mt][nt], 0, 0, 0);
            }
        }

        // ---- kk = 3 : k = 96..99 live (qd==0), 100..127 masked to zero ----
        {
            const bool live = (qd == 0);
            const float4 wA = *(const float4*)(w1g + 96);   // uniform, in-bounds
            const float4 cA = *(const float4*)(b1g + 96);
            const h2v wh0 = live ? pkrtz(wA.x, wA.y) : z2;
            const h2v wh1 = live ? pkrtz(wA.z, wA.w) : z2;
            const h2v ch0 = live ? pkrtz(cA.x, cA.y) : z2;
            const h2v ch1 = live ? pkrtz(cA.z, cA.w) : z2;

            half8 bf[4];
#pragma unroll
            for (int nt = 0; nt < 4; ++nt) {
                // reads beyond k=100 hit next row's data: harmless, A side = 0
                const float* rowp = Wsh + osrc[nt] * NH1 + 96 + qd * 8;
                const float4 u0 = *(const float4*)(rowp);
                h2v* bp = (h2v*)&bf[nt];
                bp[0] = pkrtz(u0.x, u0.y); bp[1] = pkrtz(u0.z, u0.w);
                bp[2] = z2;                bp[3] = z2;
            }
#pragma unroll
            for (int mt = 0; mt < 4; ++mt) {
                half8 af;
                h2v* ap = (h2v*)&af;
                ap[0] = __builtin_elementwise_max(wh0 * xh[mt] + ch0, z2);
                ap[1] = __builtin_elementwise_max(wh1 * xh[mt] + ch1, z2);
                ap[2] = z2;
                ap[3] = z2;
#pragma unroll
                for (int nt = 0; nt < 4; ++nt)
                    acc[mt][nt] = __builtin_amdgcn_mfma_f32_16x16x32_f16(
                        af, bf[nt], acc[mt][nt], 0, 0, 0);
            }
        }

        // epilogue for this f: h2 = relu(acc + b2); rp += h2 * w3
        const float* __restrict__ b2g = b2 + f * NH2;
        const float* __restrict__ w3g = W3 + f * NH2;
#pragma unroll
        for (int nt = 0; nt < 4; ++nt) {
            const int o = nt * 16 + ln;
            const float bo = b2g[osrc[nt]];
            const float wo = (o < NH2) ? w3g[osrc[nt]] : 0.f;
#pragma unroll
            for (int mt = 0; mt < 4; ++mt)
#pragma unroll
                for (int r = 0; r < 4; ++r)
                    rp[mt][r] = fmaf(fmaxf(acc[mt][nt][r] + bo, 0.f), wo, rp[mt][r]);
        }
    }

    // ---- shuffle-reduce rp over the 16 columns, one atomic per row ----
#pragma unroll
    for (int mt = 0; mt < 4; ++mt)
#pragma unroll
        for (int r = 0; r < 4; ++r) {
            float v = rp[mt][r];
            v += __shfl_xor(v, 1);
            v += __shfl_xor(v, 2);
            v += __shfl_xor(v, 4);
            v += __shfl_xor(v, 8);
            if (ln == 0)
                atomicAdd(out + rowbase + mt * 16 + qd * 4 + r, v);
        }
}

__global__ __launch_bounds__(256) void nam_finish(
    float* __restrict__ out, const float* __restrict__ bias)
{
    const int b = blockIdx.x * blockDim.x + threadIdx.x;
    out[b] = 1.0f / (1.0f + expf(-(out[b] + bias[0])));
}

extern "C" void kernel_launch(void* const* d_in, const int* in_sizes, int n_in,
                              void* d_out, int out_size, void* d_ws, size_t ws_size,
                              hipStream_t stream) {
    const float* x    = (const float*)d_in[0];
    const float* W1   = (const float*)d_in[1];
    const float* b1   = (const float*)d_in[2];
    const float* W2   = (const float*)d_in[3];
    const float* b2   = (const float*)d_in[4];
    const float* W3   = (const float*)d_in[5];
    const float* bias = (const float*)d_in[6];
    float* out = (float*)d_out;
    // d_ws deliberately untouched (ws-free graph, R1-shape)

    (void)hipMemsetAsync(out, 0, (size_t)BATCH * sizeof(float), stream);

    nam_mfma<<<dim3(BATCH / RPB, NFEAT / FPB), 256, 0, stream>>>(
        x, W1, b1, W2, b2, W3, out);

    nam_finish<<<BATCH / 256, 256, 0, stream>>>(out, bias);
}

// Round 18
// 127.780 us; speedup vs baseline: 1.5489x; 1.2134x over previous
//
#include <hip/hip_runtime.h>
#include <math.h>

// Problem constants
#define BATCH 8192
#define NFEAT 256
#define NH1   100     // fc1 width (K of fc2)
#define NH2   50      // fc2 width (N of fc2)
#define KP    128     // K padded: 4 MFMA k-steps of 32
#define FPB   8       // features per block (inner loop)
#define RPB   256     // batch rows per block (64 per wave)

typedef __attribute__((ext_vector_type(8))) _Float16 half8;   // MFMA A/B frag
typedef __attribute__((ext_vector_type(2))) _Float16 h2v;     // packed fp16 pair
typedef __attribute__((ext_vector_type(2))) __fp16   fp16x2;  // cvt_pkrtz result
typedef __attribute__((ext_vector_type(4))) float    float4v; // MFMA acc

__device__ __forceinline__ h2v pkrtz(float a, float b) {
    fp16x2 r = __builtin_amdgcn_cvt_pkrtz(a, b);
    return __builtin_bit_cast(h2v, r);
}

// ---- workspace layout (fp32 units from ws start) ----
// w2h : NFEAT*8192 f16 = 4 MB (fragment-ordered, zero-padded)
// w1h/b1h : NFEAT*KP f16 (zero-padded)
#define OFF_W1H  (NFEAT * 8192 / 2)
#define OFF_B1H  (OFF_W1H + NFEAT * KP / 2)

// ---- prep v2 (R16, neutral-or-better): grid = (4 kk-quarters, NFEAT).
// Coalesced W2 slice -> LDS (stride 40, 2-way aliasing = free) -> coalesced
// fragment-ordered fp16 stores.
__global__ __launch_bounds__(256) void prep(
    const float* __restrict__ W1, const float* __restrict__ b1,
    const float* __restrict__ W2, float* __restrict__ ws,
    float* __restrict__ out)
{
    __shared__ float l2[NH2 * 40];       // 8 KB
    const int q = blockIdx.x;            // kk quarter 0..3
    const int f = blockIdx.y;
    const int t = threadIdx.x;

    if (q == 0) {
        _Float16* w1h = (_Float16*)(ws + OFF_W1H) + f * KP;
        _Float16* b1h = (_Float16*)(ws + OFF_B1H) + f * KP;
        if (t < KP) {
            w1h[t] = (_Float16)((t < NH1) ? W1[f * NH1 + t] : 0.f);
            b1h[t] = (_Float16)((t < NH1) ? b1[f * NH1 + t] : 0.f);
        }
        if (t < 32) out[f * 32 + t] = 0.f;
    }

    const float* __restrict__ w2g = W2 + (size_t)f * NH2 * NH1;
#pragma unroll
    for (int i = 0; i < 7; ++i) {
        const int idx = i * 256 + t;
        if (idx < NH2 * 32) {
            const int o = idx >> 5, hh = idx & 31, h = q * 32 + hh;
            l2[o * 40 + hh] = (h < NH1) ? w2g[o * NH1 + h] : 0.f;
        }
    }
    __syncthreads();

    _Float16* w2h = (_Float16*)ws + (size_t)f * 8192 + q * 2048;
#pragma unroll
    for (int i = 0; i < 8; ++i) {
        const int el   = i * 256 + t;          // 0..2047
        const int j    = el & 7;
        const int lane = (el >> 3) & 63;
        const int nt   = (el >> 9) & 3;
        const int o    = nt * 16 + (lane & 15);
        const int hl   = (lane >> 4) * 8 + j;
        w2h[el] = (_Float16)((o < NH2) ? l2[o * 40 + hl] : 0.f);
    }
}

// async 16KB stage: 4 x (256 lanes x 16B) global->LDS DMA, zero VGPRs.
__device__ __forceinline__ void stage_async(
    const _Float16* __restrict__ src, _Float16* dst, int t)
{
#pragma unroll
    for (int i = 0; i < 4; ++i) {
        const _Float16* g = src + (i * 256 + t) * 8;
        _Float16* l       = dst + (i * 256 + t) * 8;
        __builtin_amdgcn_global_load_lds(
            (const __attribute__((address_space(1))) unsigned*)g,
            (__attribute__((address_space(3))) unsigned*)l, 16, 0, 0);
    }
}

// ---- main: EXACT R13 body + ONLY double-buffered async staging (clean A/B;
// R15 proved the ticket — not async staging — caused R14's regression).
// f+1's DMA issued at loop top, drained by the single iteration-end barrier.
// No ticket, no fence, no persistent staging registers, unroll-1 fi loop.
__global__ __launch_bounds__(256, 3) void nam_mfma(
    const float* __restrict__ x,
    const float* __restrict__ ws,
    const float* __restrict__ b2,
    const float* __restrict__ W3,
    float* __restrict__ out)
{
    __shared__ _Float16 lds[2][8192];      // 2 x 16 KB fragment buffers

    const int t   = threadIdx.x;
    const int wv  = t >> 6;
    const int l64 = t & 63;
    const int ln  = t & 15;
    const int qd  = (t >> 4) & 3;
    const int rowbase = blockIdx.x * RPB + wv * 64;
    const int f0      = blockIdx.y * FPB;

    const _Float16* w2h = (const _Float16*)ws;
    const _Float16* w1h = (const _Float16*)(ws + OFF_W1H);
    const _Float16* b1h = (const _Float16*)(ws + OFF_B1H);

    int osrc[4];
#pragma unroll
    for (int nt = 0; nt < 4; ++nt) {
        const int o = nt * 16 + ln;
        osrc[nt] = (o < NH2) ? o : 0;      // clamped; killed by wo=0
    }

    stage_async(w2h + (size_t)f0 * 8192, lds[0], t);
    __syncthreads();

    float rp[4][4] = {{0.f}, {0.f}, {0.f}, {0.f}};   // contrib, summed over f

#pragma unroll 1
    for (int fi = 0; fi < FPB; ++fi) {
        const int f = f0 + fi;
        const _Float16* B = lds[fi & 1];

        // DMA f+1 into the other buffer; lands by this iter's end barrier
        if (fi + 1 < FPB)
            stage_async(w2h + (size_t)(f + 1) * 8192, lds[(fi + 1) & 1], t);

        // x for this feature (same 64B line across fi -> L1-hot)
        h2v xh[4];
#pragma unroll
        for (int mt = 0; mt < 4; ++mt) {
            const float xs = x[(size_t)(rowbase + mt * 16 + ln) * NFEAT + f];
            xh[mt] = pkrtz(xs, xs);
        }

        float4v acc[4][4];
#pragma unroll
        for (int mt = 0; mt < 4; ++mt)
#pragma unroll
            for (int nt = 0; nt < 4; ++nt) acc[mt][nt] = (float4v){0.f, 0.f, 0.f, 0.f};

        const h2v* wp = (const h2v*)(w1h + f * KP);
        const h2v* cp = (const h2v*)(b1h + f * KP);
        const h2v z2 = (h2v){(_Float16)0.f, (_Float16)0.f};

#pragma unroll
        for (int kk = 0; kk < 4; ++kk) {
            half8 bf[4];
#pragma unroll
            for (int nt = 0; nt < 4; ++nt)
                bf[nt] = *(const half8*)(B + (kk * 4 + nt) * 512 + l64 * 8);

            const int pb = kk * 16 + qd * 4;       // h2v pair index
            const h2v w0 = wp[pb], w1 = wp[pb + 1], w2 = wp[pb + 2], w3 = wp[pb + 3];
            const h2v c0 = cp[pb], c1 = cp[pb + 1], c2 = cp[pb + 2], c3 = cp[pb + 3];

#pragma unroll
            for (int mt = 0; mt < 4; ++mt) {
                half8 af;
                h2v* ap = (h2v*)&af;
                ap[0] = __builtin_elementwise_max(w0 * xh[mt] + c0, z2);
                ap[1] = __builtin_elementwise_max(w1 * xh[mt] + c1, z2);
                ap[2] = __builtin_elementwise_max(w2 * xh[mt] + c2, z2);
                ap[3] = __builtin_elementwise_max(w3 * xh[mt] + c3, z2);
#pragma unroll
                for (int nt = 0; nt < 4; ++nt)
                    acc[mt][nt] = __builtin_amdgcn_mfma_f32_16x16x32_f16(
                        af, bf[nt], acc[mt][nt], 0, 0, 0);
            }
        }

        // epilogue for this f: h2 = relu(acc + b2); rp += h2 * w3
        const float* __restrict__ b2g = b2 + f * NH2;
        const float* __restrict__ w3g = W3 + f * NH2;
#pragma unroll
        for (int nt = 0; nt < 4; ++nt) {
            const int o = nt * 16 + ln;
            const float bo = b2g[osrc[nt]];
            const float wo = (o < NH2) ? w3g[osrc[nt]] : 0.f;
#pragma unroll
            for (int mt = 0; mt < 4; ++mt)
#pragma unroll
                for (int r = 0; r < 4; ++r)
                    rp[mt][r] = fmaf(fmaxf(acc[mt][nt][r] + bo, 0.f), wo, rp[mt][r]);
        }

        __syncthreads();   // drains DMA (f+1 ready) + releases buffer fi&1
    }

    // ---- shuffle-reduce rp over the 16 columns, one atomic per row ----
#pragma unroll
    for (int mt = 0; mt < 4; ++mt)
#pragma unroll
        for (int r = 0; r < 4; ++r) {
            float v = rp[mt][r];
            v += __shfl_xor(v, 1);
            v += __shfl_xor(v, 2);
            v += __shfl_xor(v, 4);
            v += __shfl_xor(v, 8);
            if (ln == 0)
                atomicAdd(out + rowbase + mt * 16 + qd * 4 + r, v);
        }
}

__global__ __launch_bounds__(256) void nam_finish(
    float* __restrict__ out, const float* __restrict__ bias)
{
    const int b = blockIdx.x * blockDim.x + threadIdx.x;
    out[b] = 1.0f / (1.0f + expf(-(out[b] + bias[0])));
}

extern "C" void kernel_launch(void* const* d_in, const int* in_sizes, int n_in,
                              void* d_out, int out_size, void* d_ws, size_t ws_size,
                              hipStream_t stream) {
    const float* x    = (const float*)d_in[0];
    const float* W1   = (const float*)d_in[1];
    const float* b1   = (const float*)d_in[2];
    const float* W2   = (const float*)d_in[3];
    const float* b2   = (const float*)d_in[4];
    const float* W3   = (const float*)d_in[5];
    const float* bias = (const float*)d_in[6];
    float* out = (float*)d_out;
    float* ws  = (float*)d_ws;   // ~4.3 MB used

    prep<<<dim3(4, NFEAT), 256, 0, stream>>>(W1, b1, W2, ws, out);

    nam_mfma<<<dim3(BATCH / RPB, NFEAT / FPB), 256, 0, stream>>>(
        x, ws, b2, W3, out);

    nam_finish<<<BATCH / 256, 256, 0, stream>>>(out, bias);
}